// Round 9
// baseline (468.251 us; speedup 1.0000x reference)
//
#include <hip/hip_runtime.h>

#define NN 100000
#define EE 1600000
#define GG 64
#define HH 128
#define BN_EPS 1e-5f

#define CB 782            // coarse buckets = ceil(NN/128), bucket = dst>>7
#define NB 256            // tiles for hist/scatter passes
#define TILE 6250         // EE / NB exactly

typedef unsigned short ushort_t;

// round-to-nearest-even fp32 -> bf16 (finite values)
static __device__ inline ushort_t f2bf(float f) {
    unsigned u = __float_as_uint(f);
    unsigned r = (u + 0x7FFF + ((u >> 16) & 1)) >> 16;
    return (ushort_t)r;
}
static __device__ inline float bf2f(ushort_t b) {
    return __uint_as_float(((unsigned)b) << 16);
}

// ---------------- graph prep: atomic-free two-level counting sort ----------------

__global__ __launch_bounds__(256) void k_hist(const int* __restrict__ ei,
                                              int* __restrict__ histG) {
    __shared__ int h[CB];
    int t = threadIdx.x;
    for (int i = t; i < CB; i += 256) h[i] = 0;
    __syncthreads();
    int e0 = blockIdx.x * TILE;
    for (int i = t; i < TILE; i += 256) {
        int d = ei[EE + e0 + i];
        atomicAdd(&h[d >> 7], 1);
    }
    __syncthreads();
    for (int i = t; i < CB; i += 256) histG[blockIdx.x * CB + i] = h[i];
}

__global__ __launch_bounds__(NB) void k_bscan(int* __restrict__ histG,
                                              int* __restrict__ total) {
    __shared__ int sh[NB];
    int t = threadIdx.x;
    int c = blockIdx.x;
    sh[t] = histG[t * CB + c];
    __syncthreads();
    for (int d = 1; d < NB; d <<= 1) {
        int x = (t >= d) ? sh[t - d] : 0;
        __syncthreads();
        sh[t] += x;
        __syncthreads();
    }
    histG[t * CB + c] = (t > 0) ? sh[t - 1] : 0;
    if (t == NB - 1) total[c] = sh[NB - 1];
}

__global__ __launch_bounds__(1024) void k_cbase(const int* __restrict__ total,
                                                int* __restrict__ cbase) {
    __shared__ int sh[1024];
    int t = threadIdx.x;
    sh[t] = (t < CB) ? total[t] : 0;
    __syncthreads();
    for (int d = 1; d < 1024; d <<= 1) {
        int x = (t >= d) ? sh[t - d] : 0;
        __syncthreads();
        sh[t] += x;
        __syncthreads();
    }
    if (t < CB) cbase[t] = (t > 0) ? sh[t - 1] : 0;
    if (t == CB - 1) cbase[CB] = sh[t];   // == EE
}

__global__ __launch_bounds__(256) void k_cscatter(const int* __restrict__ ei,
                                                  const int* __restrict__ histG,
                                                  const int* __restrict__ cbase,
                                                  int* __restrict__ metaS) {
    __shared__ int base_l[CB];
    __shared__ int cur_l[CB];
    int t = threadIdx.x;
    int b = blockIdx.x;
    for (int i = t; i < CB; i += 256) {
        base_l[i] = cbase[i] + histG[b * CB + i];
        cur_l[i] = 0;
    }
    __syncthreads();
    int e0 = b * TILE;
    for (int i = t; i < TILE; i += 256) {
        int s = ei[e0 + i];
        int d = ei[EE + e0 + i];
        int c = d >> 7;
        int p = base_l[c] + atomicAdd(&cur_l[c], 1);
        metaS[p] = s | ((d & 127) << 17);
    }
}

// pass D: fine histogram, cnt/offs, sorted col; dinv fused at the end
__global__ __launch_bounds__(256) void k_fine(const int* __restrict__ metaS,
                                              const int* __restrict__ cbase,
                                              int* __restrict__ cnt,
                                              int* __restrict__ offs,
                                              int* __restrict__ col,
                                              float* __restrict__ dinv) {
    __shared__ int hist[128];
    __shared__ int scn[128];
    __shared__ int cur[128];
    int t = threadIdx.x;
    int c = blockIdx.x;
    int lo = cbase[c], hi = cbase[c + 1];
    if (t < 128) hist[t] = 0;
    __syncthreads();
    for (int r = lo + t; r < hi; r += 256) atomicAdd(&hist[metaS[r] >> 17], 1);
    __syncthreads();
    if (t < 128) scn[t] = hist[t];
    __syncthreads();
    for (int d = 1; d < 128; d <<= 1) {
        int x = (t >= d && t < 128) ? scn[t - d] : 0;
        __syncthreads();
        if (t < 128) scn[t] += x;
        __syncthreads();
    }
    if (t < 128) {
        int excl = (t > 0) ? scn[t - 1] : 0;
        cur[t] = excl;
        int node = c * 128 + t;
        if (node < NN) {
            cnt[node] = hist[t];
            offs[node] = lo + excl;
            dinv[node] = rsqrtf((float)(hist[t] + 1));   // +1 self loop
        }
    }
    __syncthreads();
    for (int r = lo + t; r < hi; r += 256) {
        int pk = metaS[r];
        int s = pk & 0x1FFFF;
        int idx = atomicAdd(&cur[pk >> 17], 1);
        col[lo + idx] = s;
    }
}

// ---------------- fused layer1+layer2: x-agg (+wgt store) -> h1 tile -> @W2 -> t2 ----

__global__ __launch_bounds__(256) void k_l12(const float* __restrict__ x,
                                             const int* __restrict__ offs,
                                             const int* __restrict__ cnt,
                                             const int* __restrict__ col,
                                             const float* __restrict__ dinv,
                                             float* __restrict__ wgt,
                                             const float* __restrict__ W1,
                                             const float* __restrict__ b1,
                                             const float* __restrict__ g1,
                                             const float* __restrict__ bb1,
                                             const float* __restrict__ m1,
                                             const float* __restrict__ v1,
                                             const float* __restrict__ W2,
                                             ushort_t* __restrict__ outB) {
    __shared__ float xs[64][132];
    __shared__ float4 ag[64];
    int tid = threadIdx.x;
    int row0 = blockIdx.x * 64;
    int hw = tid >> 5;          // 0..7
    int l = tid & 31;
    // phase 0: aggregate x for 8 nodes per half-wave; materialize edge weights
    for (int k = 0; k < 8; k++) {
        int r = hw * 8 + k;
        int d = row0 + r;
        float a0 = 0.f, a1 = 0.f, a2 = 0.f;
        if (d < NN) {
            float dv = dinv[d];
            int base = offs[d], cn2 = cnt[d];
            for (int i = l; i < cn2; i += 32) {
                int s = col[base + i];
                float w = dinv[s] * dv;
                wgt[base + i] = w;
                a0 += w * x[s * 3 + 0];
                a1 += w * x[s * 3 + 1];
                a2 += w * x[s * 3 + 2];
            }
#pragma unroll
            for (int off = 16; off >= 1; off >>= 1) {
                a0 += __shfl_xor(a0, off, 32);
                a1 += __shfl_xor(a1, off, 32);
                a2 += __shfl_xor(a2, off, 32);
            }
            if (l == 0) {
                float w0 = dv * dv;
                a0 += w0 * x[d * 3 + 0];
                a1 += w0 * x[d * 3 + 1];
                a2 += w0 * x[d * 3 + 2];
                ag[r] = make_float4(a0, a1, a2, 0.f);
            }
        } else if (l == 0) {
            ag[r] = make_float4(0.f, 0.f, 0.f, 0.f);
        }
    }
    __syncthreads();
    // phase 1: h1 tile
    {
        int c = tid & 127;
        int rh = tid >> 7;
        float w0 = W1[c], w1 = W1[128 + c], w2 = W1[256 + c];
        float sc = g1[c] * rsqrtf(v1[c] + BN_EPS);
        float sh = (b1[c] - m1[c]) * sc + bb1[c];
#pragma unroll
        for (int i = 0; i < 32; i++) {
            int r = 2 * i + rh;
            float4 a = ag[r];
            float t = a.x * w0 + a.y * w1 + a.z * w2;
            xs[r][c] = fmaxf(t * sc + sh, 0.f);
        }
    }
    __syncthreads();
    // phase 2: matmul by W2, row-major bf16 out
    int tx = tid & 31;
    int ty = tid >> 5;
    float acc[8][4];
#pragma unroll
    for (int i = 0; i < 8; i++)
#pragma unroll
        for (int j = 0; j < 4; j++) acc[i][j] = 0.f;
    const float* Wp = W2 + tx * 4;
#pragma unroll 4
    for (int k = 0; k < 128; k++) {
        float4 w = *(const float4*)&Wp[k * HH];
#pragma unroll
        for (int i = 0; i < 8; i++) {
            float xv = xs[ty * 8 + i][k];
            acc[i][0] += xv * w.x;
            acc[i][1] += xv * w.y;
            acc[i][2] += xv * w.z;
            acc[i][3] += xv * w.w;
        }
    }
#pragma unroll
    for (int i = 0; i < 8; i++) {
        int gr = row0 + ty * 8 + i;
        if (gr < NN) {
            ushort4 o;
            o.x = f2bf(acc[i][0]);
            o.y = f2bf(acc[i][1]);
            o.z = f2bf(acc[i][2]);
            o.w = f2bf(acc[i][3]);
            *(ushort4*)&outB[(size_t)gr * HH + tx * 4] = o;
        }
    }
}

// ---------------- gather-aggregate (bf16 rows) + bias + BN + ReLU, bf16 out ------
// R5-proven structure: half-wave (32 lanes) per node, lane = 4 bf16 ch, unroll 8.

__global__ __launch_bounds__(256) void k_agg(const ushort_t* __restrict__ t,
                                             const int* __restrict__ offs,
                                             const int* __restrict__ cnt,
                                             const int* __restrict__ col,
                                             const float* __restrict__ wgt,
                                             const float* __restrict__ dinv,
                                             const float* __restrict__ bias,
                                             const float* __restrict__ g,
                                             const float* __restrict__ bb,
                                             const float* __restrict__ m,
                                             const float* __restrict__ v,
                                             ushort_t* __restrict__ out) {
    int wave = threadIdx.x >> 6;
    int lane = threadIdx.x & 63;
    int half = lane >> 5;
    int l = lane & 31;
    int d = blockIdx.x * 8 + wave * 2 + half;    // NN % 8 == 0
    int c0 = l * 4;
    float dv = dinv[d];
    float w0 = dv * dv;
    ushort4 selfR = *(const ushort4*)&t[(size_t)d * HH + c0];
    float4 acc;
    acc.x = bf2f(selfR.x) * w0; acc.y = bf2f(selfR.y) * w0;
    acc.z = bf2f(selfR.z) * w0; acc.w = bf2f(selfR.w) * w0;
    int base = offs[d], cn = cnt[d];
    for (int ib = 0; ib < cn; ib += 32) {
        int i = ib + l;
        int s = 0;
        float w = 0.f;
        if (i < cn) {
            s = col[base + i];
            w = wgt[base + i];
        }
        int lim = min(32, cn - ib);
#pragma unroll 8
        for (int j = 0; j < lim; j++) {
            int ss = __shfl(s, j, 32);
            float ww = __shfl(w, j, 32);
            ushort4 tv = *(const ushort4*)&t[(size_t)ss * HH + c0];
            acc.x += ww * bf2f(tv.x);
            acc.y += ww * bf2f(tv.y);
            acc.z += ww * bf2f(tv.z);
            acc.w += ww * bf2f(tv.w);
        }
    }
    float4 gg = *(const float4*)&g[c0];
    float4 vv = *(const float4*)&v[c0];
    float4 mm = *(const float4*)&m[c0];
    float4 bv = *(const float4*)&bb[c0];
    float4 bi = *(const float4*)&bias[c0];
    float sc0 = gg.x * rsqrtf(vv.x + BN_EPS);
    float sc1 = gg.y * rsqrtf(vv.y + BN_EPS);
    float sc2 = gg.z * rsqrtf(vv.z + BN_EPS);
    float sc3 = gg.w * rsqrtf(vv.w + BN_EPS);
    ushort4 o;
    o.x = f2bf(fmaxf(acc.x * sc0 + (bi.x - mm.x) * sc0 + bv.x, 0.f));
    o.y = f2bf(fmaxf(acc.y * sc1 + (bi.y - mm.y) * sc1 + bv.y, 0.f));
    o.z = f2bf(fmaxf(acc.z * sc2 + (bi.z - mm.z) * sc2 + bv.z, 0.f));
    o.w = f2bf(fmaxf(acc.w * sc3 + (bi.w - mm.w) * sc3 + bv.w, 0.f));
    *(ushort4*)&out[(size_t)d * HH + c0] = o;
}

// ---------------- dense 128x128 matmul, row-major bf16 in / bf16 out ----------------

__global__ __launch_bounds__(256) void k_mm(const ushort_t* __restrict__ xin,
                                            const float* __restrict__ W,
                                            ushort_t* __restrict__ outB) {
    __shared__ float xs[64][132];
    int tid = threadIdx.x;
    int tx = tid & 31;
    int ty = tid >> 5;
    int row0 = blockIdx.x * 64;
#pragma unroll
    for (int i = 0; i < 4; i++) {
        int idx8 = i * 256 + tid;        // 0..1023 ushort8 slots
        int r = idx8 >> 4;               // 16 slots per row
        int k8 = (idx8 & 15) * 8;
        int gr = row0 + r;
        int4 pk = (gr < NN) ? *(const int4*)&xin[(size_t)gr * HH + k8]
                            : make_int4(0, 0, 0, 0);
        float* dst = &xs[r][k8];
        dst[0] = __uint_as_float(((unsigned)pk.x) << 16);
        dst[1] = __uint_as_float(((unsigned)pk.x) & 0xFFFF0000u);
        dst[2] = __uint_as_float(((unsigned)pk.y) << 16);
        dst[3] = __uint_as_float(((unsigned)pk.y) & 0xFFFF0000u);
        dst[4] = __uint_as_float(((unsigned)pk.z) << 16);
        dst[5] = __uint_as_float(((unsigned)pk.z) & 0xFFFF0000u);
        dst[6] = __uint_as_float(((unsigned)pk.w) << 16);
        dst[7] = __uint_as_float(((unsigned)pk.w) & 0xFFFF0000u);
    }
    __syncthreads();
    float acc[8][4];
#pragma unroll
    for (int i = 0; i < 8; i++)
#pragma unroll
        for (int j = 0; j < 4; j++) acc[i][j] = 0.f;

    const float* Wp = W + tx * 4;
#pragma unroll 4
    for (int k = 0; k < 128; k++) {
        float4 w = *(const float4*)&Wp[k * HH];
#pragma unroll
        for (int i = 0; i < 8; i++) {
            float xv = xs[ty * 8 + i][k];
            acc[i][0] += xv * w.x;
            acc[i][1] += xv * w.y;
            acc[i][2] += xv * w.z;
            acc[i][3] += xv * w.w;
        }
    }
#pragma unroll
    for (int i = 0; i < 8; i++) {
        int gr = row0 + ty * 8 + i;
        if (gr < NN) {
            ushort4 o;
            o.x = f2bf(acc[i][0]);
            o.y = f2bf(acc[i][1]);
            o.z = f2bf(acc[i][2]);
            o.w = f2bf(acc[i][3]);
            *(ushort4*)&outB[(size_t)gr * HH + tx * 4] = o;
        }
    }
}

// ---------------- gather(l3) + BN + ReLU + fused mean-pool (R5 agg + LDS epilogue) ----

__global__ __launch_bounds__(256) void k_aggpool(const ushort_t* __restrict__ t,
                                                 const int* __restrict__ offs,
                                                 const int* __restrict__ cnt,
                                                 const int* __restrict__ col,
                                                 const float* __restrict__ wgt,
                                                 const float* __restrict__ dinv,
                                                 const float* __restrict__ bias,
                                                 const float* __restrict__ g,
                                                 const float* __restrict__ bb,
                                                 const float* __restrict__ m,
                                                 const float* __restrict__ v,
                                                 const int* __restrict__ batch,
                                                 float* __restrict__ gsum,
                                                 int* __restrict__ gcnt) {
    __shared__ float sh[8][128];
    __shared__ int bsh[8];
    int wave = threadIdx.x >> 6;
    int lane = threadIdx.x & 63;
    int half = lane >> 5;
    int l = lane & 31;
    int r = wave * 2 + half;                     // 0..7
    int d = blockIdx.x * 8 + r;                  // NN % 8 == 0
    int c0 = l * 4;
    if (threadIdx.x < 8) bsh[threadIdx.x] = batch[blockIdx.x * 8 + threadIdx.x];
    float dv = dinv[d];
    float w0 = dv * dv;
    ushort4 selfR = *(const ushort4*)&t[(size_t)d * HH + c0];
    float4 acc;
    acc.x = bf2f(selfR.x) * w0; acc.y = bf2f(selfR.y) * w0;
    acc.z = bf2f(selfR.z) * w0; acc.w = bf2f(selfR.w) * w0;
    int base = offs[d], cn = cnt[d];
    for (int ib = 0; ib < cn; ib += 32) {
        int i = ib + l;
        int s = 0;
        float w = 0.f;
        if (i < cn) {
            s = col[base + i];
            w = wgt[base + i];
        }
        int lim = min(32, cn - ib);
#pragma unroll 8
        for (int j = 0; j < lim; j++) {
            int ss = __shfl(s, j, 32);
            float ww = __shfl(w, j, 32);
            ushort4 tv = *(const ushort4*)&t[(size_t)ss * HH + c0];
            acc.x += ww * bf2f(tv.x);
            acc.y += ww * bf2f(tv.y);
            acc.z += ww * bf2f(tv.z);
            acc.w += ww * bf2f(tv.w);
        }
    }
    float4 gg = *(const float4*)&g[c0];
    float4 vv = *(const float4*)&v[c0];
    float4 mm = *(const float4*)&m[c0];
    float4 bv = *(const float4*)&bb[c0];
    float4 bi = *(const float4*)&bias[c0];
    float sc0 = gg.x * rsqrtf(vv.x + BN_EPS);
    float sc1 = gg.y * rsqrtf(vv.y + BN_EPS);
    float sc2 = gg.z * rsqrtf(vv.z + BN_EPS);
    float sc3 = gg.w * rsqrtf(vv.w + BN_EPS);
    float4 o;
    o.x = fmaxf(acc.x * sc0 + (bi.x - mm.x) * sc0 + bv.x, 0.f);
    o.y = fmaxf(acc.y * sc1 + (bi.y - mm.y) * sc1 + bv.y, 0.f);
    o.z = fmaxf(acc.z * sc2 + (bi.z - mm.z) * sc2 + bv.z, 0.f);
    o.w = fmaxf(acc.w * sc3 + (bi.w - mm.w) * sc3 + bv.w, 0.f);
    *(float4*)&sh[r][c0] = o;
    __syncthreads();
    // per-channel run-reduction over the 8 sorted batch ids
    if (threadIdx.x < 128) {
        int c = threadIdx.x;
        float a = 0.f;
        int cur = bsh[0];
#pragma unroll
        for (int rr = 0; rr < 8; rr++) {
            int g2 = bsh[rr];
            if (g2 != cur) {
                atomicAdd(&gsum[cur * HH + c], a);
                a = 0.f; cur = g2;
            }
            a += sh[rr][c];
        }
        atomicAdd(&gsum[cur * HH + c], a);
    } else if (threadIdx.x == 128) {
        int cur = bsh[0];
        int count = 0;
#pragma unroll
        for (int rr = 0; rr < 8; rr++) {
            int g2 = bsh[rr];
            if (g2 != cur) {
                atomicAdd(&gcnt[cur], count);
                count = 0; cur = g2;
            }
            count++;
        }
        atomicAdd(&gcnt[cur], count);
    }
}

__global__ void k_head(const float* __restrict__ gsum, const int* __restrict__ gcnt,
                       const float* __restrict__ linW, const float* __restrict__ linb,
                       float* __restrict__ out) {
    int t = threadIdx.x;        // 128 = 64 graphs x 2 outputs
    int gr = t >> 1, j = t & 1;
    float inv = 1.0f / fmaxf((float)gcnt[gr], 1.0f);
    float acc = 0.f;
    for (int c = 0; c < HH; c++) acc += gsum[gr * HH + c] * linW[c * 2 + j];
    out[t] = acc * inv + linb[j];
}

// ---------------- host launch ----------------

static inline size_t al256(size_t x) { return (x + 255) & ~(size_t)255; }

extern "C" void kernel_launch(void* const* d_in, const int* in_sizes, int n_in,
                              void* d_out, int out_size, void* d_ws, size_t ws_size,
                              hipStream_t stream) {
    const float* x    = (const float*)d_in[0];
    const int*   ei   = (const int*)d_in[1];
    const int*   batch= (const int*)d_in[2];
    const float* W1   = (const float*)d_in[3];
    const float* b1   = (const float*)d_in[4];
    const float* W2   = (const float*)d_in[5];
    const float* b2   = (const float*)d_in[6];
    const float* W3   = (const float*)d_in[7];
    const float* b3   = (const float*)d_in[8];
    const float* linW = (const float*)d_in[9];
    const float* linb = (const float*)d_in[10];
    const float* bn1g = (const float*)d_in[11];
    const float* bn1b = (const float*)d_in[12];
    const float* bn1m = (const float*)d_in[13];
    const float* bn1v = (const float*)d_in[14];
    const float* bn2g = (const float*)d_in[15];
    const float* bn2b = (const float*)d_in[16];
    const float* bn2m = (const float*)d_in[17];
    const float* bn2v = (const float*)d_in[18];
    const float* bn3g = (const float*)d_in[19];
    const float* bn3b = (const float*)d_in[20];
    const float* bn3m = (const float*)d_in[21];
    const float* bn3v = (const float*)d_in[22];
    float* out = (float*)d_out;

    char* ws = (char*)d_ws;
    size_t off = 0;
    int*    histG  = (int*)(ws + off);    off += al256((size_t)NB * CB * 4);
    int*    total  = (int*)(ws + off);    off += al256((size_t)CB * 4);
    int*    cbase  = (int*)(ws + off);    off += al256((size_t)(CB + 1) * 4);
    int*    cnt    = (int*)(ws + off);    off += al256((size_t)NN * 4);
    int*    offs   = (int*)(ws + off);    off += al256((size_t)NN * 4);
    float*  dinv   = (float*)(ws + off);  off += al256((size_t)NN * 4);
    int*    col    = (int*)(ws + off);    off += al256((size_t)(EE + 64) * 4);
    float*  wgt    = (float*)(ws + off);  off += al256((size_t)(EE + 64) * 4);
    char*   buf2   = (char*)(ws + off);   off += al256((size_t)NN * HH * 2);  // t2 / t3 (also metaS)
    char*   buf3   = (char*)(ws + off);   off += al256((size_t)NN * HH * 2);  // h2
    float*  gsum   = (float*)(ws + off);  off += (size_t)GG * HH * 4;
    int*    gcnt   = (int*)(ws + off);    off += al256((size_t)GG * 4);

    // metaS (coarse-sorted packed edges, 6.4MB) overlays buf2:
    // fully consumed by k_fine before k_l12 writes t2.
    int* metaS = (int*)buf2;
    ushort_t* t2 = (ushort_t*)buf2;   // row-major [NN][128] bf16
    ushort_t* h2 = (ushort_t*)buf3;   // row-major [NN][128] bf16

    hipMemsetAsync(gsum, 0, (size_t)GG * HH * 4 + (size_t)GG * 4, stream);

    // atomic-free counting sort -> CSR (+ dinv fused into k_fine)
    k_hist<<<NB, 256, 0, stream>>>(ei, histG);
    k_bscan<<<CB, NB, 0, stream>>>(histG, total);
    k_cbase<<<1, 1024, 0, stream>>>(total, cbase);
    k_cscatter<<<NB, 256, 0, stream>>>(ei, histG, cbase, metaS);
    k_fine<<<CB, 256, 0, stream>>>(metaS, cbase, cnt, offs, col, dinv);

    int nblk64 = (NN + 63) / 64;   // 1563

    // layer 1+2 fused: x-agg (+wgt materialize) -> h1 -> @W2 -> t2
    k_l12<<<nblk64, 256, 0, stream>>>(x, offs, cnt, col, dinv, wgt,
                                      W1, b1, bn1g, bn1b, bn1m, bn1v, W2, t2);

    // layer-2 aggregate: t2 -> h2 (R5-proven kernel)
    k_agg<<<NN / 8, 256, 0, stream>>>(t2, offs, cnt, col, wgt, dinv,
                                      b2, bn2g, bn2b, bn2m, bn2v, h2);

    // layer-3 matmul: h2 @ W3 -> t3 (into buf2, t2 dead)
    k_mm<<<nblk64, 256, 0, stream>>>(h2, W3, t2);

    // layer-3 aggregate + fused mean-pool
    k_aggpool<<<NN / 8, 256, 0, stream>>>(t2, offs, cnt, col, wgt, dinv,
                                          b3, bn3g, bn3b, bn3m, bn3v,
                                          batch, gsum, gcnt);

    k_head<<<1, 128, 0, stream>>>(gsum, gcnt, linW, linb, out);
}

// Round 10
// 443.391 us; speedup vs baseline: 1.0561x; 1.0561x over previous
//
#include <hip/hip_runtime.h>

#define NN 100000
#define EE 1600000
#define GG 64
#define HH 128
#define BN_EPS 1e-5f

#define CB 782            // coarse buckets = ceil(NN/128), bucket = dst>>7
#define NB 256            // tiles for hist/scatter passes
#define TILE 6250         // EE / NB exactly

typedef unsigned short ushort_t;

// round-to-nearest-even fp32 -> bf16 (finite values)
static __device__ inline ushort_t f2bf(float f) {
    unsigned u = __float_as_uint(f);
    unsigned r = (u + 0x7FFF + ((u >> 16) & 1)) >> 16;
    return (ushort_t)r;
}
static __device__ inline float bf2f(ushort_t b) {
    return __uint_as_float(((unsigned)b) << 16);
}

// ---------------- graph prep: atomic-free two-level counting sort ----------------

__global__ __launch_bounds__(256) void k_hist(const int* __restrict__ ei,
                                              int* __restrict__ histG) {
    __shared__ int h[CB];
    int t = threadIdx.x;
    for (int i = t; i < CB; i += 256) h[i] = 0;
    __syncthreads();
    int e0 = blockIdx.x * TILE;
    for (int i = t; i < TILE; i += 256) {
        int d = ei[EE + e0 + i];
        atomicAdd(&h[d >> 7], 1);
    }
    __syncthreads();
    for (int i = t; i < CB; i += 256) histG[blockIdx.x * CB + i] = h[i];
}

__global__ __launch_bounds__(NB) void k_bscan(int* __restrict__ histG,
                                              int* __restrict__ total) {
    __shared__ int sh[NB];
    int t = threadIdx.x;
    int c = blockIdx.x;
    sh[t] = histG[t * CB + c];
    __syncthreads();
    for (int d = 1; d < NB; d <<= 1) {
        int x = (t >= d) ? sh[t - d] : 0;
        __syncthreads();
        sh[t] += x;
        __syncthreads();
    }
    histG[t * CB + c] = (t > 0) ? sh[t - 1] : 0;
    if (t == NB - 1) total[c] = sh[NB - 1];
}

__global__ __launch_bounds__(1024) void k_cbase(const int* __restrict__ total,
                                                int* __restrict__ cbase) {
    __shared__ int sh[1024];
    int t = threadIdx.x;
    sh[t] = (t < CB) ? total[t] : 0;
    __syncthreads();
    for (int d = 1; d < 1024; d <<= 1) {
        int x = (t >= d) ? sh[t - d] : 0;
        __syncthreads();
        sh[t] += x;
        __syncthreads();
    }
    if (t < CB) cbase[t] = (t > 0) ? sh[t - 1] : 0;
    if (t == CB - 1) cbase[CB] = sh[t];   // == EE
}

__global__ __launch_bounds__(256) void k_cscatter(const int* __restrict__ ei,
                                                  const int* __restrict__ histG,
                                                  const int* __restrict__ cbase,
                                                  int* __restrict__ metaS) {
    __shared__ int base_l[CB];
    __shared__ int cur_l[CB];
    int t = threadIdx.x;
    int b = blockIdx.x;
    for (int i = t; i < CB; i += 256) {
        base_l[i] = cbase[i] + histG[b * CB + i];
        cur_l[i] = 0;
    }
    __syncthreads();
    int e0 = b * TILE;
    for (int i = t; i < TILE; i += 256) {
        int s = ei[e0 + i];
        int d = ei[EE + e0 + i];
        int c = d >> 7;
        int p = base_l[c] + atomicAdd(&cur_l[c], 1);
        metaS[p] = s | ((d & 127) << 17);
    }
}

// pass D: fine histogram, cnt/offs, sorted col; dinv fused at the end
__global__ __launch_bounds__(256) void k_fine(const int* __restrict__ metaS,
                                              const int* __restrict__ cbase,
                                              int* __restrict__ cnt,
                                              int* __restrict__ offs,
                                              int* __restrict__ col,
                                              float* __restrict__ dinv) {
    __shared__ int hist[128];
    __shared__ int scn[128];
    __shared__ int cur[128];
    int t = threadIdx.x;
    int c = blockIdx.x;
    int lo = cbase[c], hi = cbase[c + 1];
    if (t < 128) hist[t] = 0;
    __syncthreads();
    for (int r = lo + t; r < hi; r += 256) atomicAdd(&hist[metaS[r] >> 17], 1);
    __syncthreads();
    if (t < 128) scn[t] = hist[t];
    __syncthreads();
    for (int d = 1; d < 128; d <<= 1) {
        int x = (t >= d && t < 128) ? scn[t - d] : 0;
        __syncthreads();
        if (t < 128) scn[t] += x;
        __syncthreads();
    }
    if (t < 128) {
        int excl = (t > 0) ? scn[t - 1] : 0;
        cur[t] = excl;
        int node = c * 128 + t;
        if (node < NN) {
            cnt[node] = hist[t];
            offs[node] = lo + excl;
            dinv[node] = rsqrtf((float)(hist[t] + 1));   // +1 self loop
        }
    }
    __syncthreads();
    for (int r = lo + t; r < hi; r += 256) {
        int pk = metaS[r];
        int s = pk & 0x1FFFF;
        int idx = atomicAdd(&cur[pk >> 17], 1);
        col[lo + idx] = s;
    }
}

// ---------------- fused layer1+layer2: x-agg (+wgt store) -> h1 tile -> @W2 -> t2 ----

__global__ __launch_bounds__(256) void k_l12(const float* __restrict__ x,
                                             const int* __restrict__ offs,
                                             const int* __restrict__ cnt,
                                             const int* __restrict__ col,
                                             const float* __restrict__ dinv,
                                             float* __restrict__ wgt,
                                             const float* __restrict__ W1,
                                             const float* __restrict__ b1,
                                             const float* __restrict__ g1,
                                             const float* __restrict__ bb1,
                                             const float* __restrict__ m1,
                                             const float* __restrict__ v1,
                                             const float* __restrict__ W2,
                                             ushort_t* __restrict__ outB) {
    __shared__ float xs[64][132];
    __shared__ float4 ag[64];
    int tid = threadIdx.x;
    int row0 = blockIdx.x * 64;
    int hw = tid >> 5;          // 0..7
    int l = tid & 31;
    // phase 0: aggregate x for 8 nodes per half-wave; materialize edge weights
    for (int k = 0; k < 8; k++) {
        int r = hw * 8 + k;
        int d = row0 + r;
        float a0 = 0.f, a1 = 0.f, a2 = 0.f;
        if (d < NN) {
            float dv = dinv[d];
            int base = offs[d], cn2 = cnt[d];
            for (int i = l; i < cn2; i += 32) {
                int s = col[base + i];
                float w = dinv[s] * dv;
                wgt[base + i] = w;
                a0 += w * x[s * 3 + 0];
                a1 += w * x[s * 3 + 1];
                a2 += w * x[s * 3 + 2];
            }
#pragma unroll
            for (int off = 16; off >= 1; off >>= 1) {
                a0 += __shfl_xor(a0, off, 32);
                a1 += __shfl_xor(a1, off, 32);
                a2 += __shfl_xor(a2, off, 32);
            }
            if (l == 0) {
                float w0 = dv * dv;
                a0 += w0 * x[d * 3 + 0];
                a1 += w0 * x[d * 3 + 1];
                a2 += w0 * x[d * 3 + 2];
                ag[r] = make_float4(a0, a1, a2, 0.f);
            }
        } else if (l == 0) {
            ag[r] = make_float4(0.f, 0.f, 0.f, 0.f);
        }
    }
    __syncthreads();
    // phase 1: h1 tile
    {
        int c = tid & 127;
        int rh = tid >> 7;
        float w0 = W1[c], w1 = W1[128 + c], w2 = W1[256 + c];
        float sc = g1[c] * rsqrtf(v1[c] + BN_EPS);
        float sh = (b1[c] - m1[c]) * sc + bb1[c];
#pragma unroll
        for (int i = 0; i < 32; i++) {
            int r = 2 * i + rh;
            float4 a = ag[r];
            float t = a.x * w0 + a.y * w1 + a.z * w2;
            xs[r][c] = fmaxf(t * sc + sh, 0.f);
        }
    }
    __syncthreads();
    // phase 2: matmul by W2, row-major bf16 out
    int tx = tid & 31;
    int ty = tid >> 5;
    float acc[8][4];
#pragma unroll
    for (int i = 0; i < 8; i++)
#pragma unroll
        for (int j = 0; j < 4; j++) acc[i][j] = 0.f;
    const float* Wp = W2 + tx * 4;
#pragma unroll 4
    for (int k = 0; k < 128; k++) {
        float4 w = *(const float4*)&Wp[k * HH];
#pragma unroll
        for (int i = 0; i < 8; i++) {
            float xv = xs[ty * 8 + i][k];
            acc[i][0] += xv * w.x;
            acc[i][1] += xv * w.y;
            acc[i][2] += xv * w.z;
            acc[i][3] += xv * w.w;
        }
    }
#pragma unroll
    for (int i = 0; i < 8; i++) {
        int gr = row0 + ty * 8 + i;
        if (gr < NN) {
            ushort4 o;
            o.x = f2bf(acc[i][0]);
            o.y = f2bf(acc[i][1]);
            o.z = f2bf(acc[i][2]);
            o.w = f2bf(acc[i][3]);
            *(ushort4*)&outB[(size_t)gr * HH + tx * 4] = o;
        }
    }
}

// ---------------- gather-aggregate (bf16 rows) + bias + BN + ReLU, bf16 out ------
// R5-proven structure: half-wave (32 lanes) per node, lane = 4 bf16 ch, unroll 8.
// NO barrier after the gather loop (R6/R9 lesson).

__global__ __launch_bounds__(256) void k_agg(const ushort_t* __restrict__ t,
                                             const int* __restrict__ offs,
                                             const int* __restrict__ cnt,
                                             const int* __restrict__ col,
                                             const float* __restrict__ wgt,
                                             const float* __restrict__ dinv,
                                             const float* __restrict__ bias,
                                             const float* __restrict__ g,
                                             const float* __restrict__ bb,
                                             const float* __restrict__ m,
                                             const float* __restrict__ v,
                                             ushort_t* __restrict__ out) {
    int wave = threadIdx.x >> 6;
    int lane = threadIdx.x & 63;
    int half = lane >> 5;
    int l = lane & 31;
    int d = blockIdx.x * 8 + wave * 2 + half;    // NN % 8 == 0
    int c0 = l * 4;
    float dv = dinv[d];
    float w0 = dv * dv;
    ushort4 selfR = *(const ushort4*)&t[(size_t)d * HH + c0];
    float4 acc;
    acc.x = bf2f(selfR.x) * w0; acc.y = bf2f(selfR.y) * w0;
    acc.z = bf2f(selfR.z) * w0; acc.w = bf2f(selfR.w) * w0;
    int base = offs[d], cn = cnt[d];
    for (int ib = 0; ib < cn; ib += 32) {
        int i = ib + l;
        int s = 0;
        float w = 0.f;
        if (i < cn) {
            s = col[base + i];
            w = wgt[base + i];
        }
        int lim = min(32, cn - ib);
#pragma unroll 8
        for (int j = 0; j < lim; j++) {
            int ss = __shfl(s, j, 32);
            float ww = __shfl(w, j, 32);
            ushort4 tv = *(const ushort4*)&t[(size_t)ss * HH + c0];
            acc.x += ww * bf2f(tv.x);
            acc.y += ww * bf2f(tv.y);
            acc.z += ww * bf2f(tv.z);
            acc.w += ww * bf2f(tv.w);
        }
    }
    float4 gg = *(const float4*)&g[c0];
    float4 vv = *(const float4*)&v[c0];
    float4 mm = *(const float4*)&m[c0];
    float4 bv = *(const float4*)&bb[c0];
    float4 bi = *(const float4*)&bias[c0];
    float sc0 = gg.x * rsqrtf(vv.x + BN_EPS);
    float sc1 = gg.y * rsqrtf(vv.y + BN_EPS);
    float sc2 = gg.z * rsqrtf(vv.z + BN_EPS);
    float sc3 = gg.w * rsqrtf(vv.w + BN_EPS);
    ushort4 o;
    o.x = f2bf(fmaxf(acc.x * sc0 + (bi.x - mm.x) * sc0 + bv.x, 0.f));
    o.y = f2bf(fmaxf(acc.y * sc1 + (bi.y - mm.y) * sc1 + bv.y, 0.f));
    o.z = f2bf(fmaxf(acc.z * sc2 + (bi.z - mm.z) * sc2 + bv.z, 0.f));
    o.w = f2bf(fmaxf(acc.w * sc3 + (bi.w - mm.w) * sc3 + bv.w, 0.f));
    *(ushort4*)&out[(size_t)d * HH + c0] = o;
}

// ---------------- dense 128x128 matmul, row-major bf16 in / bf16 out ----------------

__global__ __launch_bounds__(256) void k_mm(const ushort_t* __restrict__ xin,
                                            const float* __restrict__ W,
                                            ushort_t* __restrict__ outB) {
    __shared__ float xs[64][132];
    int tid = threadIdx.x;
    int tx = tid & 31;
    int ty = tid >> 5;
    int row0 = blockIdx.x * 64;
#pragma unroll
    for (int i = 0; i < 4; i++) {
        int idx8 = i * 256 + tid;        // 0..1023 ushort8 slots
        int r = idx8 >> 4;               // 16 slots per row
        int k8 = (idx8 & 15) * 8;
        int gr = row0 + r;
        int4 pk = (gr < NN) ? *(const int4*)&xin[(size_t)gr * HH + k8]
                            : make_int4(0, 0, 0, 0);
        float* dst = &xs[r][k8];
        dst[0] = __uint_as_float(((unsigned)pk.x) << 16);
        dst[1] = __uint_as_float(((unsigned)pk.x) & 0xFFFF0000u);
        dst[2] = __uint_as_float(((unsigned)pk.y) << 16);
        dst[3] = __uint_as_float(((unsigned)pk.y) & 0xFFFF0000u);
        dst[4] = __uint_as_float(((unsigned)pk.z) << 16);
        dst[5] = __uint_as_float(((unsigned)pk.z) & 0xFFFF0000u);
        dst[6] = __uint_as_float(((unsigned)pk.w) << 16);
        dst[7] = __uint_as_float(((unsigned)pk.w) & 0xFFFF0000u);
    }
    __syncthreads();
    float acc[8][4];
#pragma unroll
    for (int i = 0; i < 8; i++)
#pragma unroll
        for (int j = 0; j < 4; j++) acc[i][j] = 0.f;

    const float* Wp = W + tx * 4;
#pragma unroll 4
    for (int k = 0; k < 128; k++) {
        float4 w = *(const float4*)&Wp[k * HH];
#pragma unroll
        for (int i = 0; i < 8; i++) {
            float xv = xs[ty * 8 + i][k];
            acc[i][0] += xv * w.x;
            acc[i][1] += xv * w.y;
            acc[i][2] += xv * w.z;
            acc[i][3] += xv * w.w;
        }
    }
#pragma unroll
    for (int i = 0; i < 8; i++) {
        int gr = row0 + ty * 8 + i;
        if (gr < NN) {
            ushort4 o;
            o.x = f2bf(acc[i][0]);
            o.y = f2bf(acc[i][1]);
            o.z = f2bf(acc[i][2]);
            o.w = f2bf(acc[i][3]);
            *(ushort4*)&outB[(size_t)gr * HH + tx * 4] = o;
        }
    }
}

// ---------------- mean pool (bf16 in, fp32 accum; sorted batch run-reduction) -------

#define PBLK 2048
__global__ void k_pool(const ushort_t* __restrict__ h, const int* __restrict__ batch,
                       float* __restrict__ gsum, int* __restrict__ gcnt) {
    int c = threadIdx.x;  // 128
    int per = (NN + PBLK - 1) / PBLK;
    int n0 = blockIdx.x * per;
    int n1 = min(NN, n0 + per);
    if (n0 >= NN) return;
    float acc = 0.f;
    int cur = batch[n0];
    int count = 0;
    for (int n = n0; n < n1; n++) {
        int gr = batch[n];
        if (gr != cur) {
            atomicAdd(&gsum[cur * HH + c], acc);
            if (c == 0) atomicAdd(&gcnt[cur], count);
            acc = 0.f; count = 0; cur = gr;
        }
        acc += bf2f(h[(size_t)n * HH + c]);
        count++;
    }
    atomicAdd(&gsum[cur * HH + c], acc);
    if (c == 0) atomicAdd(&gcnt[cur], count);
}

__global__ void k_head(const float* __restrict__ gsum, const int* __restrict__ gcnt,
                       const float* __restrict__ linW, const float* __restrict__ linb,
                       float* __restrict__ out) {
    int t = threadIdx.x;        // 128 = 64 graphs x 2 outputs
    int gr = t >> 1, j = t & 1;
    float inv = 1.0f / fmaxf((float)gcnt[gr], 1.0f);
    float acc = 0.f;
    for (int c = 0; c < HH; c++) acc += gsum[gr * HH + c] * linW[c * 2 + j];
    out[t] = acc * inv + linb[j];
}

// ---------------- host launch ----------------

static inline size_t al256(size_t x) { return (x + 255) & ~(size_t)255; }

extern "C" void kernel_launch(void* const* d_in, const int* in_sizes, int n_in,
                              void* d_out, int out_size, void* d_ws, size_t ws_size,
                              hipStream_t stream) {
    const float* x    = (const float*)d_in[0];
    const int*   ei   = (const int*)d_in[1];
    const int*   batch= (const int*)d_in[2];
    const float* W1   = (const float*)d_in[3];
    const float* b1   = (const float*)d_in[4];
    const float* W2   = (const float*)d_in[5];
    const float* b2   = (const float*)d_in[6];
    const float* W3   = (const float*)d_in[7];
    const float* b3   = (const float*)d_in[8];
    const float* linW = (const float*)d_in[9];
    const float* linb = (const float*)d_in[10];
    const float* bn1g = (const float*)d_in[11];
    const float* bn1b = (const float*)d_in[12];
    const float* bn1m = (const float*)d_in[13];
    const float* bn1v = (const float*)d_in[14];
    const float* bn2g = (const float*)d_in[15];
    const float* bn2b = (const float*)d_in[16];
    const float* bn2m = (const float*)d_in[17];
    const float* bn2v = (const float*)d_in[18];
    const float* bn3g = (const float*)d_in[19];
    const float* bn3b = (const float*)d_in[20];
    const float* bn3m = (const float*)d_in[21];
    const float* bn3v = (const float*)d_in[22];
    float* out = (float*)d_out;

    char* ws = (char*)d_ws;
    size_t off = 0;
    int*    histG  = (int*)(ws + off);    off += al256((size_t)NB * CB * 4);
    int*    total  = (int*)(ws + off);    off += al256((size_t)CB * 4);
    int*    cbase  = (int*)(ws + off);    off += al256((size_t)(CB + 1) * 4);
    int*    cnt    = (int*)(ws + off);    off += al256((size_t)NN * 4);
    int*    offs   = (int*)(ws + off);    off += al256((size_t)NN * 4);
    float*  dinv   = (float*)(ws + off);  off += al256((size_t)NN * 4);
    int*    col    = (int*)(ws + off);    off += al256((size_t)(EE + 64) * 4);
    float*  wgt    = (float*)(ws + off);  off += al256((size_t)(EE + 64) * 4);
    char*   buf2   = (char*)(ws + off);   off += al256((size_t)NN * HH * 2);  // t2 / t3 (also metaS)
    char*   buf3   = (char*)(ws + off);   off += al256((size_t)NN * HH * 2);  // h2 / h3
    float*  gsum   = (float*)(ws + off);  off += (size_t)GG * HH * 4;
    int*    gcnt   = (int*)(ws + off);    off += al256((size_t)GG * 4);

    // metaS (coarse-sorted packed edges, 6.4MB) overlays buf2:
    // fully consumed by k_fine before k_l12 writes t2.
    int* metaS = (int*)buf2;
    ushort_t* t2 = (ushort_t*)buf2;   // row-major [NN][128] bf16 (t2, later t3)
    ushort_t* h2 = (ushort_t*)buf3;   // row-major [NN][128] bf16 (h2, later h3)

    hipMemsetAsync(gsum, 0, (size_t)GG * HH * 4 + (size_t)GG * 4, stream);

    // atomic-free counting sort -> CSR (+ dinv fused into k_fine)
    k_hist<<<NB, 256, 0, stream>>>(ei, histG);
    k_bscan<<<CB, NB, 0, stream>>>(histG, total);
    k_cbase<<<1, 1024, 0, stream>>>(total, cbase);
    k_cscatter<<<NB, 256, 0, stream>>>(ei, histG, cbase, metaS);
    k_fine<<<CB, 256, 0, stream>>>(metaS, cbase, cnt, offs, col, dinv);

    int nblk64 = (NN + 63) / 64;   // 1563

    // layer 1+2 fused: x-agg (+wgt materialize) -> h1 -> @W2 -> t2
    k_l12<<<nblk64, 256, 0, stream>>>(x, offs, cnt, col, dinv, wgt,
                                      W1, b1, bn1g, bn1b, bn1m, bn1v, W2, t2);

    // layer-2 aggregate: t2 -> h2
    k_agg<<<NN / 8, 256, 0, stream>>>(t2, offs, cnt, col, wgt, dinv,
                                      b2, bn2g, bn2b, bn2m, bn2v, h2);

    // layer-3 matmul: h2 @ W3 -> t3 (into buf2, t2 dead)
    k_mm<<<nblk64, 256, 0, stream>>>(h2, W3, t2);

    // layer-3 aggregate: t3 -> h3 (into buf3, h2 dead)
    k_agg<<<NN / 8, 256, 0, stream>>>(t2, offs, cnt, col, wgt, dinv,
                                      b3, bn3g, bn3b, bn3m, bn3v, h2);

    // pool + head
    k_pool<<<PBLK, 128, 0, stream>>>(h2, batch, gsum, gcnt);
    k_head<<<1, 128, 0, stream>>>(gsum, gcnt, linW, linb, out);
}